// Round 11
// baseline (176.040 us; speedup 1.0000x reference)
//
#include <hip/hip_runtime.h>

#define NHEAD 12
#define DHEAD 64
#define SEQ   2048
#define NB    2
#define NX    768
#define MTOK  (NB * SEQ)   // 4096

typedef __attribute__((ext_vector_type(8))) short short8;
typedef __attribute__((ext_vector_type(4))) short short4v;
typedef __attribute__((ext_vector_type(4))) float f32x4;

__device__ __forceinline__ unsigned short f2bf(float x) {
    union { float f; unsigned u; } v; v.f = x;
    unsigned r = v.u + 0x7fffu + ((v.u >> 16) & 1u);
    return (unsigned short)(r >> 16);
}

#define MFMA32(a, b, c) __builtin_amdgcn_mfma_f32_16x16x32_bf16(a, b, c, 0, 0, 0)
#define MFMA16(a, b, c) __builtin_amdgcn_mfma_f32_16x16x16bf16_1k(a, b, c, 0, 0, 0)

// q-scale: 1/sqrt(64) * log2(e), folded so attn can use exp2 directly
#define QSCALE 0.1803368801111204f

// ---------------------------------------------------------------------------
// Merged converts (one dispatch; block-uniform branch) — unchanged from R10.
// ---------------------------------------------------------------------------
__global__ __launch_bounds__(256)
void cvt_all(const float* __restrict__ hs,
             const float* __restrict__ wa, const float* __restrict__ wp,
             unsigned short* __restrict__ Abf,
             unsigned short* __restrict__ WtA, unsigned short* __restrict__ WtP)
{
    __shared__ float tile[32][33];
    const int bid = blockIdx.x;
    const int t = threadIdx.x;

    if (bid < 3072) {
        int i = bid * 256 + t;
        if (i >= 786432) return;
        float4 v = ((const float4*)hs)[i];
        ushort4 o;
        o.x = f2bf(v.x); o.y = f2bf(v.y); o.z = f2bf(v.z); o.w = f2bf(v.w);
        ((ushort4*)Abf)[i] = o;
        return;
    }

    const float* W; unsigned short* T; int K, N, bx, by;
    if (bid < 4800) {
        int b2 = bid - 3072;               // 72 x 24
        bx = b2 % 72; by = b2 / 72;
        W = wa; T = WtA; K = NX; N = 3 * NX;
    } else {
        int b2 = bid - 4800;               // 24 x 24
        bx = b2 % 24; by = b2 / 24;
        W = wp; T = WtP; K = NX; N = NX;
    }
    const int r = t >> 5, c = t & 31;
    const int k0 = by * 32, n0 = bx * 32;
#pragma unroll
    for (int i = 0; i < 4; i++)
        tile[r + i * 8][c] = W[(size_t)(k0 + r + i * 8) * N + n0 + c];
    __syncthreads();
#pragma unroll
    for (int i = 0; i < 4; i++) {
        int n = r + i * 8;
        T[(size_t)(n0 + n) * K + k0 + c] = f2bf(tile[c][n]);
    }
}

// ---------------------------------------------------------------------------
// bf16 MFMA GEMM, R5-verified core loop. Both operands are [rows][K] bf16.
// MODE 0: token-major (A=tokens), V epilogue only -> vtb [B,H,D,S], ushort4.
// MODE 2: channel-major (A=W rows = qk channels), C[ch][tok] -> q/k
//         [B,H,S,D] with ushort4 stores (4 consecutive dims per lane).
// MODE 3: channel-major proj: out[tok][ch] float4 stores.
// ---------------------------------------------------------------------------
template<int MODE>
__global__ __launch_bounds__(256, 3)
void gemm_bf(const unsigned short* __restrict__ A,   // [M][K] bf16
             const unsigned short* __restrict__ Bt,  // [N][K] bf16
             const float* __restrict__ bias,
             float* __restrict__ fo,
             unsigned short* __restrict__ qb, unsigned short* __restrict__ kb2,
             unsigned short* __restrict__ vtb,
             int M, int N, int K)
{
    __shared__ __align__(16) unsigned char sm[2][16384];  // [buf][A 8KB | B 8KB]
    const int t = threadIdx.x;
    const int w = t >> 6, lane = t & 63;
    const int lo16 = lane & 15, quad = lane >> 4;
    const int ib = blockIdx.y * 128, jb = blockIdx.x * 128;

    f32x4 acc[4][4];
#pragma unroll
    for (int mt = 0; mt < 4; mt++)
#pragma unroll
        for (int nt = 0; nt < 4; nt++) acc[mt][nt] = (f32x4){0.f, 0.f, 0.f, 0.f};

    const int srow = lane >> 2;   // 0..15 within seg
    const int sj   = lane & 3;

    auto stage = [&](int buf, int k0) {
#pragma unroll
        for (int i = 0; i < 4; i++) {
            const int u   = i * 4 + w;
            const int p   = u >> 3;
            const int row = (u & 7) * 16 + srow;
            const int sc  = sj ^ (row & 3);
            const unsigned short* g = (p == 0)
                ? (A  + (size_t)(ib + row) * K + k0 + sc * 8)
                : (Bt + (size_t)(jb + row) * K + k0 + sc * 8);
            void* lp = &sm[buf][p * 8192 + (u & 7) * 1024];
            __builtin_amdgcn_global_load_lds(
                (const __attribute__((address_space(1))) unsigned int*)g,
                (__attribute__((address_space(3))) unsigned int*)lp, 16, 0, 0);
        }
    };

    const int mrow = (w >> 1) * 64;
    const int nrow = (w & 1) * 64;

    stage(0, 0);
    const int NIT = K / 32;
    for (int kt = 0; kt < NIT; kt++) {
        const int buf = kt & 1;
        __syncthreads();
        if (kt + 1 < NIT) stage(buf ^ 1, (kt + 1) * 32);

        short8 af[4], bf[4];
#pragma unroll
        for (int mt = 0; mt < 4; mt++) {
            const int row = mrow + mt * 16 + lo16;
            af[mt] = *(const short8*)&sm[buf][row * 64 + ((quad ^ (row & 3)) * 16)];
        }
#pragma unroll
        for (int nt = 0; nt < 4; nt++) {
            const int row = nrow + nt * 16 + lo16;
            bf[nt] = *(const short8*)&sm[buf][8192 + row * 64 + ((quad ^ (row & 3)) * 16)];
        }
#pragma unroll
        for (int mt = 0; mt < 4; mt++)
#pragma unroll
            for (int nt = 0; nt < 4; nt++)
                acc[mt][nt] = MFMA32(af[mt], bf[nt], acc[mt][nt]);
    }

    if constexpr (MODE == 0) {
        // V only (token-major): m = token, n = V channel (0..767); bias offset
        // by caller. ushort4 along s — verified R5 path.
#pragma unroll
        for (int nt = 0; nt < 4; nt++) {
            const int j  = jb + nrow + nt * 16 + lo16;   // V channel
            const int hh = j >> 6, dd = j & 63;
            const float bj = bias[j];
#pragma unroll
            for (int mt = 0; mt < 4; mt++) {
                const int m0 = ib + mrow + mt * 16 + quad * 4;
                const int bb = m0 >> 11;
                const int s0 = m0 & 2047;
                const size_t hb = (size_t)(bb * NHEAD + hh);
                ushort4 pv;
                pv.x = f2bf(acc[mt][nt][0] + bj);
                pv.y = f2bf(acc[mt][nt][1] + bj);
                pv.z = f2bf(acc[mt][nt][2] + bj);
                pv.w = f2bf(acc[mt][nt][3] + bj);
                *(ushort4*)(vtb + (hb * DHEAD + dd) * SEQ + s0) = pv;
            }
        }
    } else if constexpr (MODE == 2) {
        // q/k channel-major: m = qkv channel (0..1535), n = token.
        // Lane holds 4 consecutive channels -> ushort4 store per (mt,nt).
#pragma unroll
        for (int mt = 0; mt < 4; mt++) {
            const int ch0   = ib + mrow + mt * 16 + quad * 4;
            const int which = ch0 / NX;          // 0=q 1=k (uniform per mt)
            const int cc    = ch0 - which * NX;
            const int hh    = cc >> 6, dd = cc & 63;
            const float4 bv = *(const float4*)(bias + ch0);
            unsigned short* dst = which ? kb2 : qb;
            const float sc = which ? 1.0f : QSCALE;
#pragma unroll
            for (int nt = 0; nt < 4; nt++) {
                const int tok = jb + nrow + nt * 16 + lo16;
                const int bb  = tok >> 11;
                const int s0  = tok & 2047;
                const size_t hb = (size_t)(bb * NHEAD + hh);
                ushort4 pv;
                pv.x = f2bf((acc[mt][nt][0] + bv.x) * sc);
                pv.y = f2bf((acc[mt][nt][1] + bv.y) * sc);
                pv.z = f2bf((acc[mt][nt][2] + bv.z) * sc);
                pv.w = f2bf((acc[mt][nt][3] + bv.w) * sc);
                *(ushort4*)(dst + (hb * SEQ + s0) * DHEAD + dd) = pv;
            }
        }
    } else {
        // proj channel-major: m = out channel (0..767), n = token. float4.
#pragma unroll
        for (int mt = 0; mt < 4; mt++) {
            const int ch0   = ib + mrow + mt * 16 + quad * 4;
            const float4 bv = *(const float4*)(bias + ch0);
#pragma unroll
            for (int nt = 0; nt < 4; nt++) {
                const int tok = jb + nrow + nt * 16 + lo16;
                float4 v;
                v.x = acc[mt][nt][0] + bv.x;
                v.y = acc[mt][nt][1] + bv.y;
                v.z = acc[mt][nt][2] + bv.z;
                v.w = acc[mt][nt][3] + bv.w;
                *(float4*)(fo + (size_t)tok * NX + ch0) = v;
            }
        }
    }
}

// ---------------------------------------------------------------------------
// bf16 flash attention v6: R5-verified structure (query-split waves, DMA-
// staged double-buffered K/V, x16 PV with pinned C-reg->B-frag mapping),
// with (a) 32 queries/wave + 2-wave blocks — same LDS reads serve 2x the
// compute (LDS-read-bound per R10 counters), (b) exp2 with pre-folded scale
// and truncation v_perm P-pack (numerics verified in R7, absmax 3.66e-4).
// Grid 768 x 128 threads; 4 blocks/CU capacity, 3 resident.
// ---------------------------------------------------------------------------
__global__ __launch_bounds__(128, 2)
void attn_bf(const unsigned short* __restrict__ qb, const unsigned short* __restrict__ kb,
             const unsigned short* __restrict__ vtb, unsigned short* __restrict__ ab)
{
    __shared__ __align__(16) unsigned char sm[2][16384];  // [buf][K 8KB | V 8KB]
    const int t = threadIdx.x;
    const int w = t >> 6, lane = t & 63;   // w in {0,1}
    const int lo16 = lane & 15, quad = lane >> 4;

    // XCD-swizzled decode: same bh stays on one XCD for K/V L2 locality
    const int id = blockIdx.x;            // 768
    const int xcd = id & 7, slot = id >> 3;
    const int bh = xcd * 3 + slot % 3;
    const int q0 = (slot / 3) * 64;
    const int b = bh / NHEAD, h = bh % NHEAD;

    const unsigned short* Qb = qb  + (size_t)bh * SEQ * DHEAD;
    const unsigned short* Kb = kb  + (size_t)bh * SEQ * DHEAD;
    const unsigned short* Vb = vtb + (size_t)bh * DHEAD * SEQ;

    // Q^T B-fragments: wave w owns queries w*32 .. +31 (2 subtiles of 16)
    short8 qf[2][2];
#pragma unroll
    for (int qt = 0; qt < 2; qt++) {
        const size_t qo = (size_t)(q0 + w * 32 + qt * 16 + lo16) * DHEAD + quad * 8;
        qf[qt][0] = *(const short8*)(Qb + qo);
        qf[qt][1] = *(const short8*)(Qb + qo + 32);
    }

    // staging: 16 segs of 1KB over 2 waves (K: u=0..7, V: u=8..15); row pitch
    // 128 B (8 chunks of 16 B); chunk j holds global chunk j ^ (row&7).
    const int srow = lane >> 3;   // 0..7 within seg
    const int sj   = lane & 7;
    auto stage = [&](int buf, int k0) {
#pragma unroll
        for (int i = 0; i < 8; i++) {
            const int u   = i * 2 + w;
            const int p   = u >> 3;
            const int row = (u & 7) * 8 + srow;   // key row (K) / dim row (V)
            const int sc  = sj ^ (row & 7);
            const unsigned short* g = (p == 0)
                ? (Kb + (size_t)(k0 + row) * DHEAD + sc * 8)
                : (Vb + (size_t)row * SEQ + k0 + sc * 8);
            void* lp = &sm[buf][p * 8192 + (u & 7) * 1024];
            __builtin_amdgcn_global_load_lds(
                (const __attribute__((address_space(1))) unsigned int*)g,
                (__attribute__((address_space(3))) unsigned int*)lp, 16, 0, 0);
        }
    };

    f32x4 oacc[4][2];
#pragma unroll
    for (int dt = 0; dt < 4; dt++)
#pragma unroll
        for (int qt = 0; qt < 2; qt++) oacc[dt][qt] = (f32x4){0.f, 0.f, 0.f, 0.f};
    float lsum[2] = {0.f, 0.f};

    const unsigned sel = 0x07060302u;

    stage(0, 0);
    for (int kt = 0; kt < SEQ / 64; kt++) {
        const int buf = kt & 1;
        __syncthreads();
        if (kt + 1 < SEQ / 64) stage(buf ^ 1, (kt + 1) * 64);

        // ---- S^T = K @ Q^T: 4 key-subtiles of 16, shared K frags ----
        f32x4 s[4][2];
#pragma unroll
        for (int rt = 0; rt < 4; rt++) {
            const int row = rt * 16 + lo16;
            const int rs = row & 7;
            short8 kf0 = *(const short8*)&sm[buf][row * 128 + ((quad ^ rs) * 16)];
            short8 kf1 = *(const short8*)&sm[buf][row * 128 + (((4 + quad) ^ rs) * 16)];
#pragma unroll
            for (int qt = 0; qt < 2; qt++) {
                f32x4 a = (f32x4){0.f, 0.f, 0.f, 0.f};
                a = MFMA32(kf0, qf[qt][0], a);
                a = MFMA32(kf1, qf[qt][1], a);
                s[rt][qt] = a;
            }
        }

        // ---- p = exp2(s) (scale pre-folded); truncation v_perm pack ----
        short4v pf[4][2];
#pragma unroll
        for (int rt = 0; rt < 4; rt++)
#pragma unroll
            for (int qt = 0; qt < 2; qt++) {
                union { float f; unsigned u; } p0, p1, p2, p3;
                p0.f = __builtin_amdgcn_exp2f(s[rt][qt][0]);
                p1.f = __builtin_amdgcn_exp2f(s[rt][qt][1]);
                p2.f = __builtin_amdgcn_exp2f(s[rt][qt][2]);
                p3.f = __builtin_amdgcn_exp2f(s[rt][qt][3]);
                lsum[qt] += (p0.f + p1.f) + (p2.f + p3.f);
                union { unsigned u[2]; short4v v; } pk;
                pk.u[0] = __builtin_amdgcn_perm(p1.u, p0.u, sel);
                pk.u[1] = __builtin_amdgcn_perm(p3.u, p2.u, sel);
                pf[rt][qt] = pk.v;
            }

        // ---- O^T += V^T @ P^T (K=16 per subtile, x16 MFMA), shared V ----
#pragma unroll
        for (int dt = 0; dt < 4; dt++) {
            const int row = dt * 16 + lo16;
            const int rs = row & 7;
#pragma unroll
            for (int rt = 0; rt < 4; rt++) {
                const int ch = (2 * rt + (quad >> 1)) ^ rs;
                short4v vf = *(const short4v*)&sm[buf][8192 + row * 128 + ch * 16 + (quad & 1) * 8];
#pragma unroll
                for (int qt = 0; qt < 2; qt++)
                    oacc[dt][qt] = MFMA16(vf, pf[rt][qt], oacc[dt][qt]);
            }
        }
    }

    // deferred l reduction across quads (each quad covered disjoint keys)
#pragma unroll
    for (int qt = 0; qt < 2; qt++) {
        lsum[qt] += __shfl_xor(lsum[qt], 16);
        lsum[qt] += __shfl_xor(lsum[qt], 32);
    }

    // O^T[dim = dt*16 + quad*4 + r][query] -> ab bf16 [B,S,NX]
#pragma unroll
    for (int qt = 0; qt < 2; qt++) {
        const float inv = 1.0f / lsum[qt];
        unsigned short* dst = ab + (size_t)(b * SEQ + q0 + w * 32 + qt * 16 + lo16) * NX + h * DHEAD;
#pragma unroll
        for (int dt = 0; dt < 4; dt++) {
            ushort4 pv;
            pv.x = f2bf(oacc[dt][qt][0] * inv);
            pv.y = f2bf(oacc[dt][qt][1] * inv);
            pv.z = f2bf(oacc[dt][qt][2] * inv);
            pv.w = f2bf(oacc[dt][qt][3] * inv);
            *(ushort4*)(dst + dt * 16 + quad * 4) = pv;
        }
    }
}

// ---------------------------------------------------------------------------
extern "C" void kernel_launch(void* const* d_in, const int* in_sizes, int n_in,
                              void* d_out, int out_size, void* d_ws, size_t ws_size,
                              hipStream_t stream)
{
    const float* hs     = (const float*)d_in[0];
    const float* w_attn = (const float*)d_in[1];
    const float* b_attn = (const float*)d_in[2];
    const float* w_proj = (const float*)d_in[3];
    const float* b_proj = (const float*)d_in[4];
    float* out = (float*)d_out;

    unsigned short* wsu = (unsigned short*)d_ws;
    unsigned short* Abf  = wsu;                      // 4096*768
    unsigned short* WtA  = Abf  + 3145728;           // 2304*768
    unsigned short* WtP  = WtA  + 1769472;           // 768*768
    unsigned short* qbuf = WtP  + 589824;            // [B,H,S,D]
    unsigned short* kbuf = qbuf + 3145728;           // [B,H,S,D]
    unsigned short* vtbf = kbuf + 3145728;           // [B,H,D,S]
    unsigned short* abf  = vtbf + 3145728;           // [B,S,NX] bf16

    // merged converts (one dispatch)
    cvt_all<<<5376, 256, 0, stream>>>(hs, w_attn, w_proj, Abf, WtA, WtP);

    // q/k GEMM, channel-major (A = first 1536 rows of WtA), ushort4 stores
    gemm_bf<2><<<dim3(32, 12), 256, 0, stream>>>(
        WtA, Abf, b_attn, nullptr, qbuf, kbuf, nullptr, 1536, MTOK, NX);

    // V GEMM, token-major (verified R5 path), ushort4 stores
    gemm_bf<0><<<dim3(6, 32), 256, 0, stream>>>(
        Abf, WtA + 1536 * NX, b_attn + 1536, nullptr, nullptr, nullptr, vtbf,
        MTOK, NX, NX);

    // attention
    attn_bf<<<768, 128, 0, stream>>>(qbuf, kbuf, vtbf, abf);

    // output projection, channel-major, float4 stores
    gemm_bf<3><<<dim3(32, 6), 256, 0, stream>>>(
        WtP, abf, b_proj, out, nullptr, nullptr, nullptr, NX, MTOK, NX);
}